// Round 19
// baseline (318.843 us; speedup 1.0000x reference)
//
#include <hip/hip_runtime.h>
#include <hip/hip_bf16.h>

// B=4, S=2048, S_ENC=1024, HIDDEN=2048, H=16, KVH=4, D=128
// Phase 1: cvt hidden->bf16 ; tpose Wq ; Q = hidden_bf @ WqT   (gemm3 8-phase)
// Phase 2: cvt enc ; batched tpose Wk/Wv/Wo ; merged K/V GEMM (gemm2) ;
//          rmsnorm(K) ; attn (Q-norm fused, KVBLK=32, 26.6KB LDS) in-place ;
//          out = attn @ WoT.
//
// ROUND-17 LESSON: double-buffered attn staging with 1-barrier handoff races.
// Attn keeps the verified single-buffer stage->sync->compute->sync skeleton;
// round 19 only shrinks the tile (KVBLK=32) to lift blocks/CU 3 -> 5.

typedef short  bf16x8 __attribute__((ext_vector_type(8)));
typedef float  f32x4  __attribute__((ext_vector_type(4)));
typedef unsigned short us;

__device__ __forceinline__ us f2bf(float f) {
    union { float f; unsigned u; } v; v.f = f;
    unsigned r = v.u + 0x7fffu + ((v.u >> 16) & 1u);  // RNE
    return (us)(r >> 16);
}
__device__ __forceinline__ float bf2f(us u) {
    union { unsigned u; float f; } v; v.u = ((unsigned)u) << 16;
    return v.f;
}

typedef __attribute__((address_space(3))) unsigned int lds_u32;
typedef __attribute__((address_space(1))) const unsigned int glb_u32;

__device__ __forceinline__ void gl_lds16(const us* g, us* l) {
    __builtin_amdgcn_global_load_lds((glb_u32*)g, (lds_u32*)l, 16, 0, 0);
}

// ---------------------------------------------------------------------------
// fp32 -> bf16 convert
// ---------------------------------------------------------------------------
__launch_bounds__(256)
__global__ void cvt_kernel(const float* __restrict__ in, us* __restrict__ out) {
    size_t i = ((size_t)blockIdx.x * 256 + threadIdx.x) * 8;
    float4 v0 = *(const float4*)(in + i);
    float4 v1 = *(const float4*)(in + i + 4);
    bf16x8 h;
    h[0] = f2bf(v0.x); h[1] = f2bf(v0.y); h[2] = f2bf(v0.z); h[3] = f2bf(v0.w);
    h[4] = f2bf(v1.x); h[5] = f2bf(v1.y); h[6] = f2bf(v1.z); h[7] = f2bf(v1.w);
    *(bf16x8*)(out + i) = h;
}

// ---------------------------------------------------------------------------
// transpose + convert: out[N][K] bf16 = in[K][N] fp32.  64x64 tiles.
// ---------------------------------------------------------------------------
__device__ __forceinline__ void tpose_tile(const float* in, us* out,
                                           int K, int N, int bx, int by,
                                           int t) {
    __shared__ us tile[64][65];
    const int n0 = bx * 64;
    const int k0 = by * 64;
    const int r  = t >> 4;
    const int c4 = (t & 15) * 4;
    #pragma unroll
    for (int rr = 0; rr < 64; rr += 16) {
        float4 v = *(const float4*)(in + (size_t)(k0 + r + rr) * N + n0 + c4);
        tile[r + rr][c4 + 0] = f2bf(v.x);
        tile[r + rr][c4 + 1] = f2bf(v.y);
        tile[r + rr][c4 + 2] = f2bf(v.z);
        tile[r + rr][c4 + 3] = f2bf(v.w);
    }
    __syncthreads();
    #pragma unroll
    for (int rr = 0; rr < 64; rr += 16) {
        ushort4 o;
        o.x = tile[c4 + 0][r + rr];
        o.y = tile[c4 + 1][r + rr];
        o.z = tile[c4 + 2][r + rr];
        o.w = tile[c4 + 3][r + rr];
        *(ushort4*)(out + (size_t)(n0 + r + rr) * K + k0 + c4) = o;
    }
}

__launch_bounds__(256)
__global__ void tpose_kernel(const float* __restrict__ in, us* __restrict__ out,
                             int K, int N) {
    tpose_tile(in, out, K, N, blockIdx.x, blockIdx.y, threadIdx.x);
}

// batched: Wk (256 blocks), Wv (256), Wo (1024) in one launch
__launch_bounds__(256)
__global__ void tpose3_kernel(const float* __restrict__ Wk, us* __restrict__ WkT,
                              const float* __restrict__ Wv, us* __restrict__ WvT,
                              const float* __restrict__ Wo, us* __restrict__ WoT) {
    int id = blockIdx.x;
    if (id < 256)      tpose_tile(Wk, WkT, 2048, 512,  id & 7,          id >> 3,         threadIdx.x);
    else if (id < 512) tpose_tile(Wv, WvT, 2048, 512,  (id - 256) & 7,  (id - 256) >> 3, threadIdx.x);
    else               tpose_tile(Wo, WoT, 2048, 2048, (id - 512) & 31, (id - 512) >> 5, threadIdx.x);
}

// ---------------------------------------------------------------------------
// gemm3: 256x256 tile, BK=64, 512 thr = 8 waves (2M x 4N), 8-phase schedule
// with counted vmcnt (T3+T4), T2 both-sides swizzle, T5 setprio, T1 XCD swz.
// (unchanged from round 11 -- verified win)
// ---------------------------------------------------------------------------
#define G3_BAR  __builtin_amdgcn_s_barrier()
#define G3_LGKM asm volatile("s_waitcnt lgkmcnt(0)" ::: "memory")
#define G3_SB0  __builtin_amdgcn_sched_barrier(0)

template <int EPI>
__launch_bounds__(512, 2)
__global__ void gemm3_kernel(const us* __restrict__ A,
                             const us* __restrict__ Bt,
                             void* __restrict__ Out,
                             int M, int N, int K) {
    __shared__ __align__(16) us As[2][2][128 * 64];
    __shared__ __align__(16) us Bs[2][2][128 * 64];

    const int tid  = threadIdx.x;
    const int lane = tid & 63;
    const int w    = tid >> 6;
    const int wrow = w >> 2;
    const int wcol = w & 3;

    const int nwg  = gridDim.x * gridDim.y;
    const int bid  = blockIdx.y * gridDim.x + blockIdx.x;
    const int cpx  = nwg >> 3;
    const int swz  = (bid & 7) * cpx + (bid >> 3);
    const int row0 = (swz / gridDim.x) * 256;
    const int n0   = (swz % gridDim.x) * 256;

    const int la = lane & 15;
    const int lg = lane >> 4;
    const int sr = lane >> 3;
    const int sc = ((lane & 7) ^ sr) * 8;
    const int bs0 = ((0 + lg) ^ (la & 7)) * 8;
    const int bs1 = ((4 + lg) ^ (la & 7)) * 8;

    const int nkt = K >> 6;

#define STAGE_A(rb, k0_, dst)                                                   \
    {                                                                           \
        _Pragma("unroll")                                                       \
        for (int g = 0; g < 2; ++g) {                                           \
            int r_ = w * 16 + g * 8;                                            \
            gl_lds16(A + (size_t)((rb) + r_ + sr) * K + (k0_) + sc,             \
                     &(dst)[r_ * 64]);                                          \
        }                                                                       \
    }
#define STAGE_B(cn, k0_)                                                        \
    {                                                                           \
        us* dsth_ = &Bs[(cn)][w >> 2][0];                                       \
        _Pragma("unroll")                                                       \
        for (int g = 0; g < 4; ++g) {                                           \
            int r_ = (w & 3) * 32 + g * 8;                                      \
            gl_lds16(Bt + (size_t)(n0 + (w >> 2) * 128 + r_ + sr) * K           \
                         + (k0_) + sc,                                          \
                     &dsth_[r_ * 64]);                                          \
        }                                                                       \
    }

    f32x4 acc[8][4] = {};

    STAGE_A(row0,        0, As[0][0]);
    STAGE_A(row0 + 128,  0, As[0][1]);
    STAGE_B(0, 0);
    STAGE_A(row0,       64, As[1][0]);
    STAGE_A(row0 + 128, 64, As[1][1]);
    asm volatile("s_waitcnt vmcnt(0)" ::: "memory");
    __syncthreads();

    bf16x8 af[8][2], bg[2][2];

    for (int t = 0; t < nkt; ++t) {
        const int c  = t & 1;
        const int cn = c ^ 1;
        const int k0 = t << 6;
        const us* Ar = &As[c][wrow][0];
        const us* Br = &Bs[c][wcol >> 1][0];
        const int brow = (wcol & 1) * 64;

        // p1
        #pragma unroll
        for (int rf = 0; rf < 8; ++rf) {
            af[rf][0] = *(const bf16x8*)&Ar[(rf * 16 + la) * 64 + bs0];
            af[rf][1] = *(const bf16x8*)&Ar[(rf * 16 + la) * 64 + bs1];
        }
        #pragma unroll
        for (int j = 0; j < 2; ++j) {
            bg[j][0] = *(const bf16x8*)&Br[(brow + j * 16 + la) * 64 + bs0];
            bg[j][1] = *(const bf16x8*)&Br[(brow + j * 16 + la) * 64 + bs1];
        }
        if (t + 1 < nkt) STAGE_B(cn, k0 + 64);
        G3_BAR; G3_LGKM; G3_SB0;
        __builtin_amdgcn_s_setprio(1);
        #pragma unroll
        for (int rf = 0; rf < 4; ++rf)
            #pragma unroll
            for (int j = 0; j < 2; ++j) {
                acc[rf][j] = __builtin_amdgcn_mfma_f32_16x16x32_bf16(af[rf][0], bg[j][0], acc[rf][j], 0, 0, 0);
                acc[rf][j] = __builtin_amdgcn_mfma_f32_16x16x32_bf16(af[rf][1], bg[j][1], acc[rf][j], 0, 0, 0);
            }
        __builtin_amdgcn_s_setprio(0);
        G3_BAR;

        // p2
        if (t + 2 < nkt) STAGE_A(row0, k0 + 128, As[c][0]);
        G3_BAR;
        __builtin_amdgcn_s_setprio(1);
        #pragma unroll
        for (int rf = 4; rf < 8; ++rf)
            #pragma unroll
            for (int j = 0; j < 2; ++j) {
                acc[rf][j] = __builtin_amdgcn_mfma_f32_16x16x32_bf16(af[rf][0], bg[j][0], acc[rf][j], 0, 0, 0);
                acc[rf][j] = __builtin_amdgcn_mfma_f32_16x16x32_bf16(af[rf][1], bg[j][1], acc[rf][j], 0, 0, 0);
            }
        __builtin_amdgcn_s_setprio(0);
        G3_BAR;

        // p3
        #pragma unroll
        for (int j = 0; j < 2; ++j) {
            bg[j][0] = *(const bf16x8*)&Br[(brow + (2 + j) * 16 + la) * 64 + bs0];
            bg[j][1] = *(const bf16x8*)&Br[(brow + (2 + j) * 16 + la) * 64 + bs1];
        }
        if (t + 2 < nkt) STAGE_A(row0 + 128, k0 + 128, As[c][1]);
        G3_BAR; G3_LGKM; G3_SB0;
        __builtin_amdgcn_s_setprio(1);
        #pragma unroll
        for (int rf = 0; rf < 4; ++rf)
            #pragma unroll
            for (int j = 0; j < 2; ++j) {
                acc[rf][2 + j] = __builtin_amdgcn_mfma_f32_16x16x32_bf16(af[rf][0], bg[j][0], acc[rf][2 + j], 0, 0, 0);
                acc[rf][2 + j] = __builtin_amdgcn_mfma_f32_16x16x32_bf16(af[rf][1], bg[j][1], acc[rf][2 + j], 0, 0, 0);
            }
        __builtin_amdgcn_s_setprio(0);
        G3_BAR;

        // p4
        __builtin_amdgcn_s_setprio(1);
        #pragma unroll
        for (int rf = 4; rf < 8; ++rf)
            #pragma unroll
            for (int j = 0; j < 2; ++j) {
                acc[rf][2 + j] = __builtin_amdgcn_mfma_f32_16x16x32_bf16(af[rf][0], bg[j][0], acc[rf][2 + j], 0, 0, 0);
                acc[rf][2 + j] = __builtin_amdgcn_mfma_f32_16x16x32_bf16(af[rf][1], bg[j][1], acc[rf][2 + j], 0, 0, 0);
            }
        __builtin_amdgcn_s_setprio(0);
        if (t >= nkt - 2) { asm volatile("s_waitcnt vmcnt(0)" ::: "memory"); }
        else              { asm volatile("s_waitcnt vmcnt(2)" ::: "memory"); }
        G3_BAR;
    }

    #pragma unroll
    for (int rf = 0; rf < 8; ++rf) {
        #pragma unroll
        for (int cf = 0; cf < 4; ++cf) {
            #pragma unroll
            for (int rr = 0; rr < 4; ++rr) {
                int row_g = row0 + wrow * 128 + rf * 16 + lg * 4 + rr;
                int col_g = n0 + wcol * 64 + cf * 16 + la;
                float val = acc[rf][cf][rr];
                if (EPI == 0) ((us*)Out)[(size_t)row_g * N + col_g] = f2bf(val);
                else          ((float*)Out)[(size_t)row_g * N + col_g] = val;
            }
        }
    }
}
#undef STAGE_A
#undef STAGE_B

// ---------------------------------------------------------------------------
// gemm2 (m97 128^2 + T2 + T1) -- kept for the merged K/V GEMM (EPI=3 only).
// ---------------------------------------------------------------------------
template <int EPI>
__launch_bounds__(256)
__global__ void gemm2_kernel(const us* __restrict__ A,
                             const us* __restrict__ Bt,
                             void* __restrict__ Out,
                             void* __restrict__ Out2,
                             int M, int N, int K) {
    __shared__ __align__(16) us As[128 * 64];
    __shared__ __align__(16) us Bs[128 * 64];

    const int tid  = threadIdx.x;
    const int lane = tid & 63;
    const int wv   = tid >> 6;

    const int nwg  = gridDim.x * gridDim.y;
    const int bid  = blockIdx.y * gridDim.x + blockIdx.x;
    const int cpx  = nwg >> 3;
    const int swz  = (bid & 7) * cpx + (bid >> 3);
    const int row0 = (swz / gridDim.x) * 128;
    const int n0   = (swz % gridDim.x) * 128;

    const int wr   = (wv >> 1) * 64;
    const int wc   = (wv & 1) * 64;
    const int la   = lane & 15;
    const int lg   = lane >> 4;

    const int srow = lane >> 3;
    const int scol = (((lane & 7) ^ srow) * 8);
    const int bs0 = ((0 + lg) ^ (la & 7)) * 8;
    const int bs1 = ((4 + lg) ^ (la & 7)) * 8;

    f32x4 acc[4][4] = {};

    for (int k0 = 0; k0 < K; k0 += 64) {
        #pragma unroll
        for (int r = 0; r < 4; ++r) {
            int brow = wv * 32 + r * 8;
            gl_lds16(Bt + (size_t)(n0 + brow + srow) * K + k0 + scol, &Bs[brow * 64]);
        }
        #pragma unroll
        for (int r = 0; r < 4; ++r) {
            int arow = wv * 32 + r * 8;
            gl_lds16(A + (size_t)(row0 + arow + srow) * K + k0 + scol, &As[arow * 64]);
        }
        __syncthreads();

        bf16x8 af[2][4], bg[2][4];
        #pragma unroll
        for (int i = 0; i < 4; ++i) {
            af[0][i] = *(const bf16x8*)&As[(wr + i * 16 + la) * 64 + bs0];
            af[1][i] = *(const bf16x8*)&As[(wr + i * 16 + la) * 64 + bs1];
        }
        #pragma unroll
        for (int j = 0; j < 4; ++j) {
            bg[0][j] = *(const bf16x8*)&Bs[(wc + j * 16 + la) * 64 + bs0];
            bg[1][j] = *(const bf16x8*)&Bs[(wc + j * 16 + la) * 64 + bs1];
        }
        #pragma unroll
        for (int kk = 0; kk < 2; ++kk)
            #pragma unroll
            for (int i = 0; i < 4; ++i)
                #pragma unroll
                for (int j = 0; j < 4; ++j)
                    acc[i][j] = __builtin_amdgcn_mfma_f32_16x16x32_bf16(af[kk][i], bg[kk][j], acc[i][j], 0, 0, 0);
        __syncthreads();
    }

    #pragma unroll
    for (int i = 0; i < 4; ++i) {
        #pragma unroll
        for (int j = 0; j < 4; ++j) {
            #pragma unroll
            for (int r = 0; r < 4; ++r) {
                int row_g = row0 + wr + i * 16 + lg * 4 + r;
                int col_g = n0 + wc + j * 16 + la;
                float val = acc[i][j][r];
                if (EPI == 0) {
                    ((us*)Out)[(size_t)row_g * N + col_g] = f2bf(val);
                } else if (EPI == 2) {
                    ((float*)Out)[(size_t)row_g * N + col_g] = val;
                } else {
                    if (col_g < 512) {
                        ((us*)Out)[(size_t)row_g * 512 + col_g] = f2bf(val);
                    } else {
                        int cc  = col_g - 512;
                        int b_  = row_g >> 10, s_ = row_g & 1023;
                        int kvh = cc >> 7,     d_ = cc & 127;
                        ((us*)Out2)[(((size_t)(b_ * 4 + kvh) * 128 + d_) << 10) + s_] = f2bf(val);
                    }
                }
            }
        }
    }
}

// ---------------------------------------------------------------------------
// In-place RMS norm (128-elem segments, one wave each) + folded post-scale.
// K-only (Q norm fused into attn prologue).
// ---------------------------------------------------------------------------
__launch_bounds__(256)
__global__ void rmsnorm_kernel(us* __restrict__ x, const float* __restrict__ w,
                               int nseg, float postscale) {
    int seg  = blockIdx.x * 4 + (threadIdx.x >> 6);
    if (seg >= nseg) return;
    int lane = threadIdx.x & 63;
    size_t base = (size_t)seg * 128 + lane * 2;
    unsigned v = *(const unsigned*)&x[base];
    float x0 = bf2f((us)(v & 0xffff));
    float x1 = bf2f((us)(v >> 16));
    float s = x0 * x0 + x1 * x1;
    #pragma unroll
    for (int m = 1; m < 64; m <<= 1) s += __shfl_xor(s, m, 64);
    float rinv = rsqrtf(s * (1.0f / 128.0f) + 1e-6f) * postscale;
    x0 = x0 * rinv * w[lane * 2];
    x1 = x1 * rinv * w[lane * 2 + 1];
    unsigned o = (unsigned)f2bf(x0) | ((unsigned)f2bf(x1) << 16);
    *(unsigned*)&x[base] = o;
}

// ---------------------------------------------------------------------------
// Flash attention (non-causal, GQA 4:1), IN PLACE over Q, Q-NORM FUSED.
// Grid 1024 = (b,h) x 16 q-tiles (XCD chunk-swizzled).  256 thr = 4 waves.
//
// ROUND 19: KVBLK 64 -> 32 inside the VERIFIED single-buffer skeleton
// (stage -> sync -> compute -> sync; r17's 1-barrier dbuf handoff raced and
// is banned).  LDS 50.2 -> 26.6 KB lifts blocks/CU 3 -> 5 so other blocks'
// compute hides each block's stage-drain stall.
//   K:  gl_lds + T2 involution (r16-verified addressing, rows halved).
//   Vt: padded [128][36] (18-bank rows -> conflict-free PV reads); padding
//       breaks gl_lds contiguity, so V uses the r13-verified IMMEDIATE
//       reg->LDS staging (2 uint4/thread, not cross-compute prefetch).
// Kept: Q-norm fused prologue, exp2 no-max softmax (|S2| <= sqrt(128)*log2e
// ~= 16.4 by Cauchy-Schwarz on RMS-normed q,k -> fp32-safe, identical to
// max-subtracted), cvt_pk P-store, setprio, XCD chunk swizzle.
// ---------------------------------------------------------------------------
__launch_bounds__(256, 2)
__global__ void attn_kernel(const us* __restrict__ Q,
                            const us* __restrict__ Kb,
                            const us* __restrict__ Vt,
                            us* __restrict__ Ob,
                            const float* __restrict__ qw, float qscale) {
    __shared__ __align__(16) us Klds[32 * 128];   // linear, T2-swizzled content
    __shared__ __align__(16) us Vtlds[128 * 36];  // padded, plain content
    __shared__ __align__(16) us Plds[4][32 * 36]; // per-wave [q][key(32)+pad]

    const int tid  = threadIdx.x;
    const int bid  = (blockIdx.x & 7) * 128 + (blockIdx.x >> 3);  // XCD chunk swz
    const int qt   = bid & 15;
    const int bh   = bid >> 4;
    const int b    = bh >> 4;
    const int h    = bh & 15;
    const int kvh  = h >> 2;

    const int lane = tid & 63;
    const int wv   = tid >> 6;
    const int la   = lane & 15;
    const int lg   = lane >> 4;
    const int lb   = lg * 8;

    const int qr0 = qt * 128 + wv * 32;

    // T2 swizzled K read offsets (shorts): logical block (t*4+lg) ^ (la&7)
    const int bswK[4] = { ((0 + lg) ^ (la & 7)) * 8,  ((4 + lg) ^ (la & 7)) * 8,
                          ((8 + lg) ^ (la & 7)) * 8,  ((12 + lg) ^ (la & 7)) * 8 };

    // ---- load raw Q fragments ----
    bf16x8 aq[2][4];
    #pragma unroll
    for (int i = 0; i < 2; ++i)
        #pragma unroll
        for (int t = 0; t < 4; ++t)
            aq[i][t] = *(const bf16x8*)&Q[(size_t)(b * 2048 + qr0 + i * 16 + la) * 2048
                                          + h * 128 + t * 32 + lb];

    // ---- fused Q rms-norm (per row; cols split across lg groups) ----
    #pragma unroll
    for (int i = 0; i < 2; ++i) {
        float s = 0.0f;
        #pragma unroll
        for (int t = 0; t < 4; ++t)
            #pragma unroll
            for (int e = 0; e < 8; ++e) {
                float f = bf2f((us)aq[i][t][e]);
                s += f * f;
            }
        s += __shfl_xor(s, 16, 64);
        s += __shfl_xor(s, 32, 64);
        float rinv = rsqrtf(s * (1.0f / 128.0f) + 1e-6f) * qscale;
        #pragma unroll
        for (int t = 0; t < 4; ++t) {
            float4 w0 = *(const float4*)(qw + t * 32 + lb);
            float4 w1 = *(const float4*)(qw + t * 32 + lb + 4);
            float x0 = bf2f((us)aq[i][t][0]) * rinv * w0.x;
            float x1 = bf2f((us)aq[i][t][1]) * rinv * w0.y;
            float x2 = bf2f((us)aq[i][t][2]) * rinv * w0.z;
            float x3 = bf2f((us)aq[i][t][3]) * rinv * w0.w;
            float x4 = bf2f((us)aq[i][t][4]) * rinv * w1.x;
            float x5 = bf2f((us)aq[i][t][5]) * rinv * w1.y;
            float x6 = bf2f((us)aq[i][t][6]) * rinv * w1.z;
            float x7 = bf2f((us)aq[i][t][7]) * rinv * w1.w;
            unsigned p0, p1, p2, p3;
            asm("v_cvt_pk_bf16_f32 %0, %1, %2" : "=v"(p0) : "v"(x0), "v"(x1));
            asm("v_cvt_pk_bf16_f32 %0, %1, %2" : "=v"(p1) : "v"(x2), "v"(x3));
            asm("v_cvt_pk_bf16_f32 %0, %1, %2" : "=v"(p2) : "v"(x4), "v"(x5));
            asm("v_cvt_pk_bf16_f32 %0, %1, %2" : "=v"(p3) : "v"(x6), "v"(x7));
            aq[i][t][0] = (short)(p0 & 0xffffu); aq[i][t][1] = (short)(p0 >> 16);
            aq[i][t][2] = (short)(p1 & 0xffffu); aq[i][t][3] = (short)(p1 >> 16);
            aq[i][t][4] = (short)(p2 & 0xffffu); aq[i][t][5] = (short)(p2 >> 16);
            aq[i][t][6] = (short)(p3 & 0xffffu); aq[i][t][7] = (short)(p3 >> 16);
        }
    }

    f32x4 oacc[2][8] = {};
    float l_part[2][4] = {};

    const us* Kbase  = Kb + (size_t)(b * 1024) * 512 + kvh * 128;
    const us* Vtbase = Vt + (size_t)(b * 4 + kvh) * 128 * 1024;

    // K staging lane decomposition (gl_lds: 4 rows x 16 blocks per issue)
    const int krow_i = lane >> 4;                       // 0..3
    const int kblk   = lane & 15;

    for (int kt = 0; kt < 32; ++kt) {
        // ---- stage K tile [32 keys][128 d] via gl_lds (pre-swizzled src) ----
        #pragma unroll
        for (int g = 0; g < 2; ++g) {
            int row0 = g * 16 + wv * 4;                 // wave-uniform
            int r    = row0 + krow_i;
            gl_lds16(Kbase + (size_t)(kt * 32 + r) * 512 + ((kblk ^ (r & 7)) << 3),
                     &Klds[row0 * 128]);
        }
        // ---- stage Vt tile [128 d][32 keys] -> padded LDS (immediate) ----
        #pragma unroll
        for (int c = 0; c < 2; ++c) {
            int idx = tid + c * 256;
            int vr  = idx >> 2;                         // 0..127
            int vb  = (idx & 3) << 3;                   // 0,8,16,24 shorts
            uint4 v = *(const uint4*)(Vtbase + (size_t)vr * 1024 + kt * 32 + vb);
            *(uint4*)&Vtlds[vr * 36 + vb] = v;
        }
        __syncthreads();

        // ---- S = Q K^T (scale*log2e pre-folded into Q) ----
        f32x4 sacc[2][2] = {};
        __builtin_amdgcn_s_setprio(1);
        #pragma unroll
        for (int j = 0; j < 2; ++j) {
            bf16x8 bk[4];
            #pragma unroll
            for (int t = 0; t < 4; ++t)
                bk[t] = *(const bf16x8*)&Klds[(j * 16 + la) * 128 + bswK[t]];
            #pragma unroll
            for (int t = 0; t < 4; ++t)
                #pragma unroll
                for (int i = 0; i < 2; ++i)
                    sacc[i][j] = __builtin_amdgcn_mfma_f32_16x16x32_bf16(aq[i][t], bk[t], sacc[i][j], 0, 0, 0);
        }
        __builtin_amdgcn_s_setprio(0);

        // ---- P = 2^S (no max subtraction) + P->LDS via cvt_pk ----
        #pragma unroll
        for (int i = 0; i < 2; ++i) {
            #pragma unroll
            for (int r = 0; r < 4; ++r) {
                float p0 = __builtin_amdgcn_exp2f(sacc[i][0][r]);
                float p1 = __builtin_amdgcn_exp2f(sacc[i][1][r]);
                l_part[i][r] += p0 + p1;
                unsigned pk;
                asm("v_cvt_pk_bf16_f32 %0, %1, %2" : "=v"(pk) : "v"(p0), "v"(p1));
                int prow = (i * 16 + lg * 4 + r) * 36;
                Plds[wv][prow + la]      = (us)(pk & 0xffffu);
                Plds[wv][prow + 16 + la] = (us)(pk >> 16);
            }
        }

        // ---- O += P V ----
        __builtin_amdgcn_s_setprio(1);
        {
            bf16x8 pa[2];
            #pragma unroll
            for (int i = 0; i < 2; ++i)
                pa[i] = *(const bf16x8*)&Plds[wv][(i * 16 + la) * 36 + lb];
            #pragma unroll
            for (int df = 0; df < 8; ++df) {
                bf16x8 bv = *(const bf16x8*)&Vtlds[(df * 16 + la) * 36 + lb];
                #pragma unroll
                for (int i = 0; i < 2; ++i)
                    oacc[i][df] = __builtin_amdgcn_mfma_f32_16x16x32_bf16(pa[i], bv, oacc[i][df], 0, 0, 0);
            }
        }
        __builtin_amdgcn_s_setprio(0);
        __syncthreads();
    }

    #pragma unroll
    for (int i = 0; i < 2; ++i) {
        #pragma unroll
        for (int r = 0; r < 4; ++r) {
            float l = l_part[i][r];
            l += __shfl_xor(l, 1, 64);
            l += __shfl_xor(l, 2, 64);
            l += __shfl_xor(l, 4, 64);
            l += __shfl_xor(l, 8, 64);
            float inv = 1.0f / l;
            int row_g = b * 2048 + qr0 + i * 16 + lg * 4 + r;
            #pragma unroll
            for (int df = 0; df < 8; ++df) {
                int col_g = h * 128 + df * 16 + la;
                Ob[(size_t)row_g * 2048 + col_g] = f2bf(oacc[i][df][r] * inv);
            }
        }
    }
}

// ---------------------------------------------------------------------------
extern "C" void kernel_launch(void* const* d_in, const int* in_sizes, int n_in,
                              void* d_out, int out_size, void* d_ws, size_t ws_size,
                              hipStream_t stream) {
    const float* hidden = (const float*)d_in[0];
    const float* enc    = (const float*)d_in[1];
    const float* Wq     = (const float*)d_in[2];
    const float* Wk     = (const float*)d_in[3];
    const float* Wv     = (const float*)d_in[4];
    const float* Wo     = (const float*)d_in[5];
    const float* qw     = (const float*)d_in[6];
    const float* kw     = (const float*)d_in[7];
    float* out = (float*)d_out;

    us* ws16 = (us*)d_ws;
    us* hidden_bf = ws16;                         // 16,777,216 elems
    us* WqT       = ws16 + 16777216;              //  4,194,304
    us* Qu        = ws16 + 20971520;              // 16,777,216
    us* enc_bf    = ws16;                         //  8,388,608 (phase 2 reuse)
    us* WkT       = ws16 + 8388608;               //  1,048,576
    us* WvT       = ws16 + 9437184;               //  1,048,576
    us* WoT       = ws16 + 10485760;              //  4,194,304
    us* Kn        = ws16 + 14680064;              //  2,097,152
    us* Vt        = ws16 + 16777216;              //  2,097,152

    dim3 blk(256);
    const float qscale = 0.08838834764831845f * 1.4426950408889634f;

    // Phase 1: Q projection (8-phase 256^2 GEMM)
    cvt_kernel<<<dim3(8192), blk, 0, stream>>>(hidden, hidden_bf);
    tpose_kernel<<<dim3(32, 32), blk, 0, stream>>>(Wq, WqT, 2048, 2048);
    gemm3_kernel<0><<<dim3(8, 32), dim3(512), 0, stream>>>(hidden_bf, WqT, Qu, 8192, 2048, 2048);

    // Phase 2
    cvt_kernel<<<dim3(4096), blk, 0, stream>>>(enc, enc_bf);
    tpose3_kernel<<<dim3(1536), blk, 0, stream>>>(Wk, WkT, Wv, WvT, Wo, WoT);
    gemm2_kernel<3><<<dim3(8, 32), blk, 0, stream>>>(enc_bf, WkT, Kn, Vt, 4096, 1024, 2048);

    // K norm only (Q norm fused into attn prologue)
    rmsnorm_kernel<<<dim3(4096), blk, 0, stream>>>(Kn, kw, 4096 * 4, 1.0f);

    attn_kernel<<<dim3(1024), blk, 0, stream>>>(Qu, Kn, Vt, Qu, qw, qscale);

    gemm3_kernel<2><<<dim3(8, 32), dim3(512), 0, stream>>>(Qu, WoT, out, 8192, 2048, 2048);
}

// Round 20
// 302.054 us; speedup vs baseline: 1.0556x; 1.0556x over previous
//
#include <hip/hip_runtime.h>
#include <hip/hip_bf16.h>

// B=4, S=2048, S_ENC=1024, HIDDEN=2048, H=16, KVH=4, D=128
// prep1 (merged): cvt hidden->bf16 || tpose Wq
// gemm3<0>: Q = hidden_bf @ WqT          (8-phase 256^2)
// prep2 (merged): cvt enc || tpose Wk/Wv/Wo   (aliases dead phase-1 data)
// gemm2<3>: merged K/V GEMM ; rmsnorm(K)
// attn (r18 verified form: Q-norm fused, gl_lds+T2, single-buffer)
// gemm3<2>: out = attn @ WoT (fp32)
//
// Attn history: r6/r12 reg-prefetch -> spill; r14 8-wave -> worse; r17 dbuf
// 1-barrier handoff -> race; r19 KVBLK=32 -> barrier-count regression.
// The r18 single-buffer KVBLK=64 form (99 us) is the verified optimum.

typedef short  bf16x8 __attribute__((ext_vector_type(8)));
typedef float  f32x4  __attribute__((ext_vector_type(4)));
typedef unsigned short us;

__device__ __forceinline__ us f2bf(float f) {
    union { float f; unsigned u; } v; v.f = f;
    unsigned r = v.u + 0x7fffu + ((v.u >> 16) & 1u);  // RNE
    return (us)(r >> 16);
}
__device__ __forceinline__ float bf2f(us u) {
    union { unsigned u; float f; } v; v.u = ((unsigned)u) << 16;
    return v.f;
}

typedef __attribute__((address_space(3))) unsigned int lds_u32;
typedef __attribute__((address_space(1))) const unsigned int glb_u32;

__device__ __forceinline__ void gl_lds16(const us* g, us* l) {
    __builtin_amdgcn_global_load_lds((glb_u32*)g, (lds_u32*)l, 16, 0, 0);
}

// ---------------------------------------------------------------------------
// fp32 -> bf16 convert (one 256-thr block converts 2048 elems at block id)
// ---------------------------------------------------------------------------
__device__ __forceinline__ void cvt_block(const float* in, us* out, int id, int t) {
    size_t i = ((size_t)id * 256 + t) * 8;
    float4 v0 = *(const float4*)(in + i);
    float4 v1 = *(const float4*)(in + i + 4);
    bf16x8 h;
    h[0] = f2bf(v0.x); h[1] = f2bf(v0.y); h[2] = f2bf(v0.z); h[3] = f2bf(v0.w);
    h[4] = f2bf(v1.x); h[5] = f2bf(v1.y); h[6] = f2bf(v1.z); h[7] = f2bf(v1.w);
    *(bf16x8*)(out + i) = h;
}

// ---------------------------------------------------------------------------
// transpose + convert: out[N][K] bf16 = in[K][N] fp32.  64x64 tiles.
// ---------------------------------------------------------------------------
__device__ __forceinline__ void tpose_tile(const float* in, us* out,
                                           int K, int N, int bx, int by,
                                           int t) {
    __shared__ us tile[64][65];
    const int n0 = bx * 64;
    const int k0 = by * 64;
    const int r  = t >> 4;
    const int c4 = (t & 15) * 4;
    #pragma unroll
    for (int rr = 0; rr < 64; rr += 16) {
        float4 v = *(const float4*)(in + (size_t)(k0 + r + rr) * N + n0 + c4);
        tile[r + rr][c4 + 0] = f2bf(v.x);
        tile[r + rr][c4 + 1] = f2bf(v.y);
        tile[r + rr][c4 + 2] = f2bf(v.z);
        tile[r + rr][c4 + 3] = f2bf(v.w);
    }
    __syncthreads();
    #pragma unroll
    for (int rr = 0; rr < 64; rr += 16) {
        ushort4 o;
        o.x = tile[c4 + 0][r + rr];
        o.y = tile[c4 + 1][r + rr];
        o.z = tile[c4 + 2][r + rr];
        o.w = tile[c4 + 3][r + rr];
        *(ushort4*)(out + (size_t)(n0 + r + rr) * K + k0 + c4) = o;
    }
}

// prep1: cvt hidden (8192 blocks) || tpose Wq (1024 blocks)
__launch_bounds__(256)
__global__ void prep1_kernel(const float* __restrict__ hidden, us* __restrict__ hbf,
                             const float* __restrict__ Wq, us* __restrict__ WqT) {
    int id = blockIdx.x;
    if (id < 8192) cvt_block(hidden, hbf, id, threadIdx.x);
    else {
        int t = id - 8192;  // 1024 tiles: 32 x 32
        tpose_tile(Wq, WqT, 2048, 2048, t & 31, t >> 5, threadIdx.x);
    }
}

// prep2: cvt enc (4096) || tpose Wk (256) || Wv (256) || Wo (1024)
__launch_bounds__(256)
__global__ void prep2_kernel(const float* __restrict__ enc, us* __restrict__ ebf,
                             const float* __restrict__ Wk, us* __restrict__ WkT,
                             const float* __restrict__ Wv, us* __restrict__ WvT,
                             const float* __restrict__ Wo, us* __restrict__ WoT) {
    int id = blockIdx.x;
    if (id < 4096) { cvt_block(enc, ebf, id, threadIdx.x); return; }
    id -= 4096;
    if (id < 256)      tpose_tile(Wk, WkT, 2048, 512,  id & 7,          id >> 3,         threadIdx.x);
    else if (id < 512) tpose_tile(Wv, WvT, 2048, 512,  (id - 256) & 7,  (id - 256) >> 3, threadIdx.x);
    else               tpose_tile(Wo, WoT, 2048, 2048, (id - 512) & 31, (id - 512) >> 5, threadIdx.x);
}

// ---------------------------------------------------------------------------
// gemm3: 256x256 tile, BK=64, 512 thr = 8 waves (2M x 4N), 8-phase schedule
// with counted vmcnt (T3+T4), T2 both-sides swizzle, T5 setprio, T1 XCD swz.
// (unchanged from round 11 -- verified win)
// ---------------------------------------------------------------------------
#define G3_BAR  __builtin_amdgcn_s_barrier()
#define G3_LGKM asm volatile("s_waitcnt lgkmcnt(0)" ::: "memory")
#define G3_SB0  __builtin_amdgcn_sched_barrier(0)

template <int EPI>
__launch_bounds__(512, 2)
__global__ void gemm3_kernel(const us* __restrict__ A,
                             const us* __restrict__ Bt,
                             void* __restrict__ Out,
                             int M, int N, int K) {
    __shared__ __align__(16) us As[2][2][128 * 64];
    __shared__ __align__(16) us Bs[2][2][128 * 64];

    const int tid  = threadIdx.x;
    const int lane = tid & 63;
    const int w    = tid >> 6;
    const int wrow = w >> 2;
    const int wcol = w & 3;

    const int nwg  = gridDim.x * gridDim.y;
    const int bid  = blockIdx.y * gridDim.x + blockIdx.x;
    const int cpx  = nwg >> 3;
    const int swz  = (bid & 7) * cpx + (bid >> 3);
    const int row0 = (swz / gridDim.x) * 256;
    const int n0   = (swz % gridDim.x) * 256;

    const int la = lane & 15;
    const int lg = lane >> 4;
    const int sr = lane >> 3;
    const int sc = ((lane & 7) ^ sr) * 8;
    const int bs0 = ((0 + lg) ^ (la & 7)) * 8;
    const int bs1 = ((4 + lg) ^ (la & 7)) * 8;

    const int nkt = K >> 6;

#define STAGE_A(rb, k0_, dst)                                                   \
    {                                                                           \
        _Pragma("unroll")                                                       \
        for (int g = 0; g < 2; ++g) {                                           \
            int r_ = w * 16 + g * 8;                                            \
            gl_lds16(A + (size_t)((rb) + r_ + sr) * K + (k0_) + sc,             \
                     &(dst)[r_ * 64]);                                          \
        }                                                                       \
    }
#define STAGE_B(cn, k0_)                                                        \
    {                                                                           \
        us* dsth_ = &Bs[(cn)][w >> 2][0];                                       \
        _Pragma("unroll")                                                       \
        for (int g = 0; g < 4; ++g) {                                           \
            int r_ = (w & 3) * 32 + g * 8;                                      \
            gl_lds16(Bt + (size_t)(n0 + (w >> 2) * 128 + r_ + sr) * K           \
                         + (k0_) + sc,                                          \
                     &dsth_[r_ * 64]);                                          \
        }                                                                       \
    }

    f32x4 acc[8][4] = {};

    STAGE_A(row0,        0, As[0][0]);
    STAGE_A(row0 + 128,  0, As[0][1]);
    STAGE_B(0, 0);
    STAGE_A(row0,       64, As[1][0]);
    STAGE_A(row0 + 128, 64, As[1][1]);
    asm volatile("s_waitcnt vmcnt(0)" ::: "memory");
    __syncthreads();

    bf16x8 af[8][2], bg[2][2];

    for (int t = 0; t < nkt; ++t) {
        const int c  = t & 1;
        const int cn = c ^ 1;
        const int k0 = t << 6;
        const us* Ar = &As[c][wrow][0];
        const us* Br = &Bs[c][wcol >> 1][0];
        const int brow = (wcol & 1) * 64;

        // p1
        #pragma unroll
        for (int rf = 0; rf < 8; ++rf) {
            af[rf][0] = *(const bf16x8*)&Ar[(rf * 16 + la) * 64 + bs0];
            af[rf][1] = *(const bf16x8*)&Ar[(rf * 16 + la) * 64 + bs1];
        }
        #pragma unroll
        for (int j = 0; j < 2; ++j) {
            bg[j][0] = *(const bf16x8*)&Br[(brow + j * 16 + la) * 64 + bs0];
            bg[j][1] = *(const bf16x8*)&Br[(brow + j * 16 + la) * 64 + bs1];
        }
        if (t + 1 < nkt) STAGE_B(cn, k0 + 64);
        G3_BAR; G3_LGKM; G3_SB0;
        __builtin_amdgcn_s_setprio(1);
        #pragma unroll
        for (int rf = 0; rf < 4; ++rf)
            #pragma unroll
            for (int j = 0; j < 2; ++j) {
                acc[rf][j] = __builtin_amdgcn_mfma_f32_16x16x32_bf16(af[rf][0], bg[j][0], acc[rf][j], 0, 0, 0);
                acc[rf][j] = __builtin_amdgcn_mfma_f32_16x16x32_bf16(af[rf][1], bg[j][1], acc[rf][j], 0, 0, 0);
            }
        __builtin_amdgcn_s_setprio(0);
        G3_BAR;

        // p2
        if (t + 2 < nkt) STAGE_A(row0, k0 + 128, As[c][0]);
        G3_BAR;
        __builtin_amdgcn_s_setprio(1);
        #pragma unroll
        for (int rf = 4; rf < 8; ++rf)
            #pragma unroll
            for (int j = 0; j < 2; ++j) {
                acc[rf][j] = __builtin_amdgcn_mfma_f32_16x16x32_bf16(af[rf][0], bg[j][0], acc[rf][j], 0, 0, 0);
                acc[rf][j] = __builtin_amdgcn_mfma_f32_16x16x32_bf16(af[rf][1], bg[j][1], acc[rf][j], 0, 0, 0);
            }
        __builtin_amdgcn_s_setprio(0);
        G3_BAR;

        // p3
        #pragma unroll
        for (int j = 0; j < 2; ++j) {
            bg[j][0] = *(const bf16x8*)&Br[(brow + (2 + j) * 16 + la) * 64 + bs0];
            bg[j][1] = *(const bf16x8*)&Br[(brow + (2 + j) * 16 + la) * 64 + bs1];
        }
        if (t + 2 < nkt) STAGE_A(row0 + 128, k0 + 128, As[c][1]);
        G3_BAR; G3_LGKM; G3_SB0;
        __builtin_amdgcn_s_setprio(1);
        #pragma unroll
        for (int rf = 0; rf < 4; ++rf)
            #pragma unroll
            for (int j = 0; j < 2; ++j) {
                acc[rf][2 + j] = __builtin_amdgcn_mfma_f32_16x16x32_bf16(af[rf][0], bg[j][0], acc[rf][2 + j], 0, 0, 0);
                acc[rf][2 + j] = __builtin_amdgcn_mfma_f32_16x16x32_bf16(af[rf][1], bg[j][1], acc[rf][2 + j], 0, 0, 0);
            }
        __builtin_amdgcn_s_setprio(0);
        G3_BAR;

        // p4
        __builtin_amdgcn_s_setprio(1);
        #pragma unroll
        for (int rf = 4; rf < 8; ++rf)
            #pragma unroll
            for (int j = 0; j < 2; ++j) {
                acc[rf][2 + j] = __builtin_amdgcn_mfma_f32_16x16x32_bf16(af[rf][0], bg[j][0], acc[rf][2 + j], 0, 0, 0);
                acc[rf][2 + j] = __builtin_amdgcn_mfma_f32_16x16x32_bf16(af[rf][1], bg[j][1], acc[rf][2 + j], 0, 0, 0);
            }
        __builtin_amdgcn_s_setprio(0);
        if (t >= nkt - 2) { asm volatile("s_waitcnt vmcnt(0)" ::: "memory"); }
        else              { asm volatile("s_waitcnt vmcnt(2)" ::: "memory"); }
        G3_BAR;
    }

    #pragma unroll
    for (int rf = 0; rf < 8; ++rf) {
        #pragma unroll
        for (int cf = 0; cf < 4; ++cf) {
            #pragma unroll
            for (int rr = 0; rr < 4; ++rr) {
                int row_g = row0 + wrow * 128 + rf * 16 + lg * 4 + rr;
                int col_g = n0 + wcol * 64 + cf * 16 + la;
                float val = acc[rf][cf][rr];
                if (EPI == 0) ((us*)Out)[(size_t)row_g * N + col_g] = f2bf(val);
                else          ((float*)Out)[(size_t)row_g * N + col_g] = val;
            }
        }
    }
}
#undef STAGE_A
#undef STAGE_B

// ---------------------------------------------------------------------------
// gemm2 (m97 128^2 + T2 + T1) -- kept for the merged K/V GEMM (EPI=3 only).
// ---------------------------------------------------------------------------
template <int EPI>
__launch_bounds__(256)
__global__ void gemm2_kernel(const us* __restrict__ A,
                             const us* __restrict__ Bt,
                             void* __restrict__ Out,
                             void* __restrict__ Out2,
                             int M, int N, int K) {
    __shared__ __align__(16) us As[128 * 64];
    __shared__ __align__(16) us Bs[128 * 64];

    const int tid  = threadIdx.x;
    const int lane = tid & 63;
    const int wv   = tid >> 6;

    const int nwg  = gridDim.x * gridDim.y;
    const int bid  = blockIdx.y * gridDim.x + blockIdx.x;
    const int cpx  = nwg >> 3;
    const int swz  = (bid & 7) * cpx + (bid >> 3);
    const int row0 = (swz / gridDim.x) * 128;
    const int n0   = (swz % gridDim.x) * 128;

    const int wr   = (wv >> 1) * 64;
    const int wc   = (wv & 1) * 64;
    const int la   = lane & 15;
    const int lg   = lane >> 4;

    const int srow = lane >> 3;
    const int scol = (((lane & 7) ^ srow) * 8);
    const int bs0 = ((0 + lg) ^ (la & 7)) * 8;
    const int bs1 = ((4 + lg) ^ (la & 7)) * 8;

    f32x4 acc[4][4] = {};

    for (int k0 = 0; k0 < K; k0 += 64) {
        #pragma unroll
        for (int r = 0; r < 4; ++r) {
            int brow = wv * 32 + r * 8;
            gl_lds16(Bt + (size_t)(n0 + brow + srow) * K + k0 + scol, &Bs[brow * 64]);
        }
        #pragma unroll
        for (int r = 0; r < 4; ++r) {
            int arow = wv * 32 + r * 8;
            gl_lds16(A + (size_t)(row0 + arow + srow) * K + k0 + scol, &As[arow * 64]);
        }
        __syncthreads();

        bf16x8 af[2][4], bg[2][4];
        #pragma unroll
        for (int i = 0; i < 4; ++i) {
            af[0][i] = *(const bf16x8*)&As[(wr + i * 16 + la) * 64 + bs0];
            af[1][i] = *(const bf16x8*)&As[(wr + i * 16 + la) * 64 + bs1];
        }
        #pragma unroll
        for (int j = 0; j < 4; ++j) {
            bg[0][j] = *(const bf16x8*)&Bs[(wc + j * 16 + la) * 64 + bs0];
            bg[1][j] = *(const bf16x8*)&Bs[(wc + j * 16 + la) * 64 + bs1];
        }
        #pragma unroll
        for (int kk = 0; kk < 2; ++kk)
            #pragma unroll
            for (int i = 0; i < 4; ++i)
                #pragma unroll
                for (int j = 0; j < 4; ++j)
                    acc[i][j] = __builtin_amdgcn_mfma_f32_16x16x32_bf16(af[kk][i], bg[kk][j], acc[i][j], 0, 0, 0);
        __syncthreads();
    }

    #pragma unroll
    for (int i = 0; i < 4; ++i) {
        #pragma unroll
        for (int j = 0; j < 4; ++j) {
            #pragma unroll
            for (int r = 0; r < 4; ++r) {
                int row_g = row0 + wr + i * 16 + lg * 4 + r;
                int col_g = n0 + wc + j * 16 + la;
                float val = acc[i][j][r];
                if (EPI == 0) {
                    ((us*)Out)[(size_t)row_g * N + col_g] = f2bf(val);
                } else if (EPI == 2) {
                    ((float*)Out)[(size_t)row_g * N + col_g] = val;
                } else {
                    if (col_g < 512) {
                        ((us*)Out)[(size_t)row_g * 512 + col_g] = f2bf(val);
                    } else {
                        int cc  = col_g - 512;
                        int b_  = row_g >> 10, s_ = row_g & 1023;
                        int kvh = cc >> 7,     d_ = cc & 127;
                        ((us*)Out2)[(((size_t)(b_ * 4 + kvh) * 128 + d_) << 10) + s_] = f2bf(val);
                    }
                }
            }
        }
    }
}

// ---------------------------------------------------------------------------
// In-place RMS norm (128-elem segments, one wave each) + folded post-scale.
// K-only (Q norm fused into attn prologue).
// ---------------------------------------------------------------------------
__launch_bounds__(256)
__global__ void rmsnorm_kernel(us* __restrict__ x, const float* __restrict__ w,
                               int nseg, float postscale) {
    int seg  = blockIdx.x * 4 + (threadIdx.x >> 6);
    if (seg >= nseg) return;
    int lane = threadIdx.x & 63;
    size_t base = (size_t)seg * 128 + lane * 2;
    unsigned v = *(const unsigned*)&x[base];
    float x0 = bf2f((us)(v & 0xffff));
    float x1 = bf2f((us)(v >> 16));
    float s = x0 * x0 + x1 * x1;
    #pragma unroll
    for (int m = 1; m < 64; m <<= 1) s += __shfl_xor(s, m, 64);
    float rinv = rsqrtf(s * (1.0f / 128.0f) + 1e-6f) * postscale;
    x0 = x0 * rinv * w[lane * 2];
    x1 = x1 * rinv * w[lane * 2 + 1];
    unsigned o = (unsigned)f2bf(x0) | ((unsigned)f2bf(x1) << 16);
    *(unsigned*)&x[base] = o;
}

// ---------------------------------------------------------------------------
// Flash attention (non-causal, GQA 4:1), IN PLACE over Q, Q-NORM FUSED.
// ROUND-18 VERIFIED FORM (99 us, absmax 0.00195) -- restored verbatim.
// Grid 1024 = (b,h) x 16 q-tiles (XCD chunk-swizzled).  256 thr = 4 waves.
// K/Vt staging via global_load_lds + T2 both-sides swizzle; single-buffer,
// stage -> vmcnt(0)+barrier -> compute per tile.
// ---------------------------------------------------------------------------
__launch_bounds__(256, 2)
__global__ void attn_kernel(const us* __restrict__ Q,
                            const us* __restrict__ Kb,
                            const us* __restrict__ Vt,
                            us* __restrict__ Ob,
                            const float* __restrict__ qw, float qscale) {
    __shared__ __align__(16) us Klds[64 * 128];   // linear, T2-swizzled content
    __shared__ __align__(16) us Vtlds[128 * 64];  // linear, T2-swizzled content
    __shared__ __align__(16) us Plds[4][32 * 68];

    const int tid  = threadIdx.x;
    const int bid  = (blockIdx.x & 7) * 128 + (blockIdx.x >> 3);  // XCD chunk swz
    const int qt   = bid & 15;
    const int bh   = bid >> 4;
    const int b    = bh >> 4;
    const int h    = bh & 15;
    const int kvh  = h >> 2;

    const int lane = tid & 63;
    const int wv   = tid >> 6;
    const int la   = lane & 15;
    const int lg   = lane >> 4;
    const int lb   = lg * 8;

    const int qr0 = qt * 128 + wv * 32;

    // T2 swizzled read offsets (shorts): logical block (x*4+lg) ^ (la&7)
    const int bsw0 = ((0 + lg) ^ (la & 7)) * 8;
    const int bsw1 = ((4 + lg) ^ (la & 7)) * 8;
    const int bsw2 = ((8 + lg) ^ (la & 7)) * 8;
    const int bsw3 = ((12 + lg) ^ (la & 7)) * 8;
    const int bswK[4] = { bsw0, bsw1, bsw2, bsw3 };

    // ---- load raw Q fragments ----
    bf16x8 aq[2][4];
    #pragma unroll
    for (int i = 0; i < 2; ++i)
        #pragma unroll
        for (int t = 0; t < 4; ++t)
            aq[i][t] = *(const bf16x8*)&Q[(size_t)(b * 2048 + qr0 + i * 16 + la) * 2048
                                          + h * 128 + t * 32 + lb];

    // ---- fused Q rms-norm (per row; cols split across lg groups) ----
    #pragma unroll
    for (int i = 0; i < 2; ++i) {
        float s = 0.0f;
        #pragma unroll
        for (int t = 0; t < 4; ++t)
            #pragma unroll
            for (int e = 0; e < 8; ++e) {
                float f = bf2f((us)aq[i][t][e]);
                s += f * f;
            }
        s += __shfl_xor(s, 16, 64);
        s += __shfl_xor(s, 32, 64);
        float rinv = rsqrtf(s * (1.0f / 128.0f) + 1e-6f) * qscale;
        #pragma unroll
        for (int t = 0; t < 4; ++t) {
            float4 w0 = *(const float4*)(qw + t * 32 + lb);
            float4 w1 = *(const float4*)(qw + t * 32 + lb + 4);
            float x0 = bf2f((us)aq[i][t][0]) * rinv * w0.x;
            float x1 = bf2f((us)aq[i][t][1]) * rinv * w0.y;
            float x2 = bf2f((us)aq[i][t][2]) * rinv * w0.z;
            float x3 = bf2f((us)aq[i][t][3]) * rinv * w0.w;
            float x4 = bf2f((us)aq[i][t][4]) * rinv * w1.x;
            float x5 = bf2f((us)aq[i][t][5]) * rinv * w1.y;
            float x6 = bf2f((us)aq[i][t][6]) * rinv * w1.z;
            float x7 = bf2f((us)aq[i][t][7]) * rinv * w1.w;
            unsigned p0, p1, p2, p3;
            asm("v_cvt_pk_bf16_f32 %0, %1, %2" : "=v"(p0) : "v"(x0), "v"(x1));
            asm("v_cvt_pk_bf16_f32 %0, %1, %2" : "=v"(p1) : "v"(x2), "v"(x3));
            asm("v_cvt_pk_bf16_f32 %0, %1, %2" : "=v"(p2) : "v"(x4), "v"(x5));
            asm("v_cvt_pk_bf16_f32 %0, %1, %2" : "=v"(p3) : "v"(x6), "v"(x7));
            aq[i][t][0] = (short)(p0 & 0xffffu); aq[i][t][1] = (short)(p0 >> 16);
            aq[i][t][2] = (short)(p1 & 0xffffu); aq[i][t][3] = (short)(p1 >> 16);
            aq[i][t][4] = (short)(p2 & 0xffffu); aq[i][t][5] = (short)(p2 >> 16);
            aq[i][t][6] = (short)(p3 & 0xffffu); aq[i][t][7] = (short)(p3 >> 16);
        }
    }

    f32x4 oacc[2][8] = {};
    float l_part[2][4] = {};

    const us* Kbase  = Kb + (size_t)(b * 1024) * 512 + kvh * 128;
    const us* Vtbase = Vt + (size_t)(b * 4 + kvh) * 128 * 1024;

    // per-lane swizzled staging source offsets
    const int krow_i = lane >> 4;                       // row within 4-row issue
    const int kblk   = lane & 15;                       // 16 blocks/row (K)
    const int vrow_i = lane >> 3;                       // row within 8-row issue
    const int vblk   = lane & 7;                        // 8 blocks/row (Vt)

    for (int kt = 0; kt < 16; ++kt) {
        // ---- stage K tile [64 keys][128 d] via gl_lds (pre-swizzled src) ----
        #pragma unroll
        for (int g = 0; g < 4; ++g) {
            int row0 = wv * 16 + g * 4;                 // wave-uniform
            int r    = row0 + krow_i;
            gl_lds16(Kbase + (size_t)(kt * 64 + r) * 512 + ((kblk ^ (r & 7)) << 3),
                     &Klds[row0 * 128]);
        }
        // ---- stage Vt tile [128 d][64 keys] via gl_lds ----
        #pragma unroll
        for (int g = 0; g < 4; ++g) {
            int row0 = wv * 32 + g * 8;                 // wave-uniform
            int r    = row0 + vrow_i;
            gl_lds16(Vtbase + (size_t)r * 1024 + kt * 64 + ((vblk ^ (r & 7)) << 3),
                     &Vtlds[row0 * 64]);
        }
        __syncthreads();

        // ---- S = Q K^T (scale*log2e pre-folded into Q) ----
        f32x4 sacc[2][4] = {};
        __builtin_amdgcn_s_setprio(1);
        #pragma unroll
        for (int j = 0; j < 4; ++j) {
            bf16x8 bk[4];
            #pragma unroll
            for (int t = 0; t < 4; ++t)
                bk[t] = *(const bf16x8*)&Klds[(j * 16 + la) * 128 + bswK[t]];
            #pragma unroll
            for (int t = 0; t < 4; ++t)
                #pragma unroll
                for (int i = 0; i < 2; ++i)
                    sacc[i][j] = __builtin_amdgcn_mfma_f32_16x16x32_bf16(aq[i][t], bk[t], sacc[i][j], 0, 0, 0);
        }
        __builtin_amdgcn_s_setprio(0);

        // ---- P = 2^S (no max subtraction) ----
        #pragma unroll
        for (int i = 0; i < 2; ++i) {
            #pragma unroll
            for (int r = 0; r < 4; ++r) {
                float ls = 0.0f;
                #pragma unroll
                for (int j = 0; j < 4; ++j) {
                    float p = __builtin_amdgcn_exp2f(sacc[i][j][r]);
                    sacc[i][j][r] = p;
                    ls += p;
                }
                l_part[i][r] += ls;
            }
        }

        // ---- P -> LDS bf16 via cvt_pk pairs (wave-private; no barrier) ----
        #pragma unroll
        for (int i = 0; i < 2; ++i) {
            #pragma unroll
            for (int r = 0; r < 4; ++r) {
                int prow = (i * 16 + lg * 4 + r) * 68;
                #pragma unroll
                for (int j = 0; j < 4; j += 2) {
                    unsigned pk;
                    asm("v_cvt_pk_bf16_f32 %0, %1, %2"
                        : "=v"(pk) : "v"(sacc[i][j][r]), "v"(sacc[i][j + 1][r]));
                    Plds[wv][prow + j * 16 + la]       = (us)(pk & 0xffffu);
                    Plds[wv][prow + (j + 1) * 16 + la] = (us)(pk >> 16);
                }
            }
        }

        // ---- O += P V ----
        __builtin_amdgcn_s_setprio(1);
        #pragma unroll
        for (int ks = 0; ks < 2; ++ks) {
            bf16x8 pa[2];
            #pragma unroll
            for (int i = 0; i < 2; ++i)
                pa[i] = *(const bf16x8*)&Plds[wv][(i * 16 + la) * 68 + ks * 32 + lb];
            const int bsv = bswK[ks];  // blocks 0..7 of 8-block Vt rows
            #pragma unroll
            for (int df = 0; df < 8; ++df) {
                bf16x8 bv = *(const bf16x8*)&Vtlds[(df * 16 + la) * 64 + bsv];
                #pragma unroll
                for (int i = 0; i < 2; ++i)
                    oacc[i][df] = __builtin_amdgcn_mfma_f32_16x16x32_bf16(pa[i], bv, oacc[i][df], 0, 0, 0);
            }
        }
        __builtin_amdgcn_s_setprio(0);
        __syncthreads();
    }

    #pragma unroll
    for (int i = 0; i < 2; ++i) {
        #pragma unroll
        for (int r = 0; r < 4; ++r) {
            float l = l_part[i][r];
            l += __shfl_xor(l, 1, 64);
            l += __shfl_xor(l, 2, 64);
            l += __shfl_xor(l, 4, 64);
            l += __shfl_xor(l, 8, 64);
            float inv = 1.0f / l;
            int row_g = b * 2048 + qr0 + i * 16 + lg * 4 + r;
            #pragma unroll
            for (int df = 0; df < 8; ++df) {
                int col_g = h * 128 + df * 16 + la;
                Ob[(size_t)row_g * 2048 + col_g] = f2bf(oacc[i][df][r] * inv);
            }
        }
    }
}

// ---------------------------------------------------------------------------
extern "C" void kernel_launch(void* const* d_in, const int* in_sizes, int n_in,
                              void* d_out, int out_size, void* d_ws, size_t ws_size,
                              hipStream_t stream) {
    const float* hidden = (const float*)d_in[0];
    const float* enc    = (const float*)d_in[1];
    const float* Wq     = (const float*)d_in[2];
    const float* Wk     = (const float*)d_in[3];
    const float* Wv     = (const float*)d_in[4];
    const float* Wo     = (const float*)d_in[5];
    const float* qw     = (const float*)d_in[6];
    const float* kw     = (const float*)d_in[7];
    float* out = (float*)d_out;

    us* ws16 = (us*)d_ws;
    us* hidden_bf = ws16;                         // 16,777,216 elems
    us* WqT       = ws16 + 16777216;              //  4,194,304
    us* Qu        = ws16 + 20971520;              // 16,777,216
    us* enc_bf    = ws16;                         //  8,388,608 (phase 2 reuse)
    us* WkT       = ws16 + 8388608;               //  1,048,576
    us* WvT       = ws16 + 9437184;               //  1,048,576
    us* WoT       = ws16 + 10485760;              //  4,194,304
    us* Kn        = ws16 + 14680064;              //  2,097,152
    us* Vt        = ws16 + 16777216;              //  2,097,152

    dim3 blk(256);
    const float qscale = 0.08838834764831845f * 1.4426950408889634f;

    // Phase 1: merged prep (cvt hidden || tpose Wq), then Q projection
    prep1_kernel<<<dim3(9216), blk, 0, stream>>>(hidden, hidden_bf, Wq, WqT);
    gemm3_kernel<0><<<dim3(8, 32), dim3(512), 0, stream>>>(hidden_bf, WqT, Qu, 8192, 2048, 2048);

    // Phase 2: merged prep (cvt enc || tpose Wk/Wv/Wo; aliases dead phase-1)
    prep2_kernel<<<dim3(5632), blk, 0, stream>>>(enc, enc_bf, Wk, WkT, Wv, WvT, Wo, WoT);
    gemm2_kernel<3><<<dim3(8, 32), blk, 0, stream>>>(enc_bf, WkT, Kn, Vt, 4096, 1024, 2048);

    // K norm only (Q norm fused into attn prologue)
    rmsnorm_kernel<<<dim3(4096), blk, 0, stream>>>(Kn, kw, 4096 * 4, 1.0f);

    attn_kernel<<<dim3(1024), blk, 0, stream>>>(Qu, Kn, Vt, Qu, qw, qscale);

    gemm3_kernel<2><<<dim3(8, 32), dim3(512), 0, stream>>>(Qu, WoT, out, 8192, 2048, 2048);
}